// Round 1
// baseline (634.869 us; speedup 1.0000x reference)
//
#include <hip/hip_runtime.h>
#include <cstdint>
#include <cstddef>

// ---- types ----
typedef _Float16 h8_t  __attribute__((ext_vector_type(8)));
typedef _Float16 h4_t  __attribute__((ext_vector_type(4)));
typedef float    f32x4 __attribute__((ext_vector_type(4)));

#define B_DIM   8192
#define IN_DIM  4096
#define OUT_DIM 4096
#define BN_EPS  1e-5f
#define SLOPE   0.01f

// address-space casts for global_load_lds (C-style cast -> addrspacecast)
#define AS_G(p) ((__attribute__((address_space(1))) void*)(p))
#define AS_L(p) ((__attribute__((address_space(3))) void*)(p))

// ---------------------------------------------------------------------------
// Kernel 1: per-column partial sum / sum-of-squares over 256-row chunks.
// grid (IN/256, B/256), block 256. Thread t owns column blk.x*256+t -> fully
// coalesced row-major reads.
// ---------------------------------------------------------------------------
__global__ __launch_bounds__(256) void k_stats_partial(const float* __restrict__ x,
                                                       float* __restrict__ partial)
{
    const int col = blockIdx.x * 256 + threadIdx.x;
    const int r0  = blockIdx.y * 256;
    const float* p = x + (size_t)r0 * IN_DIM + col;
    float s = 0.f, sq = 0.f;
#pragma unroll 8
    for (int r = 0; r < 256; ++r) {
        float v = p[(size_t)r * IN_DIM];
        s  += v;
        sq += v * v;
    }
    partial[(size_t)(blockIdx.y * 2 + 0) * IN_DIM + col] = s;
    partial[(size_t)(blockIdx.y * 2 + 1) * IN_DIM + col] = sq;
}

// ---------------------------------------------------------------------------
// Kernel 2: reduce 32 partials -> scale/shift per column.
//   scale = gamma * rsqrt(var + eps);  shift = beta - mean * scale
// ---------------------------------------------------------------------------
__global__ __launch_bounds__(256) void k_stats_final(const float* __restrict__ partial,
                                                     const float* __restrict__ gamma,
                                                     const float* __restrict__ beta,
                                                     float* __restrict__ scale,
                                                     float* __restrict__ shift)
{
    const int col = blockIdx.x * 256 + threadIdx.x;
    float s = 0.f, sq = 0.f;
#pragma unroll
    for (int c = 0; c < 32; ++c) {
        s  += partial[(size_t)(c * 2 + 0) * IN_DIM + col];
        sq += partial[(size_t)(c * 2 + 1) * IN_DIM + col];
    }
    const float inv  = 1.0f / (float)B_DIM;
    const float mean = s * inv;
    const float var  = sq * inv - mean * mean;   // biased variance
    const float sc   = gamma[col] * rsqrtf(var + BN_EPS);
    scale[col] = sc;
    shift[col] = beta[col] - mean * sc;
}

// ---------------------------------------------------------------------------
// Kernel 3: H = fp16(x * scale + shift). float4 loads, half4 stores.
// ---------------------------------------------------------------------------
__global__ __launch_bounds__(256) void k_convert_h(const float* __restrict__ x,
                                                   const float* __restrict__ scale,
                                                   const float* __restrict__ shift,
                                                   _Float16* __restrict__ H)
{
    const size_t i4   = (size_t)blockIdx.x * 256 + threadIdx.x;
    const size_t base = i4 * 4;
    const int    col  = (int)(base & (IN_DIM - 1));
    const float4 xv = ((const float4*)x)[i4];
    const float4 sv = *(const float4*)(scale + col);
    const float4 tv = *(const float4*)(shift + col);
    h4_t h;
    h.x = (_Float16)fmaf(xv.x, sv.x, tv.x);
    h.y = (_Float16)fmaf(xv.y, sv.y, tv.y);
    h.z = (_Float16)fmaf(xv.z, sv.z, tv.z);
    h.w = (_Float16)fmaf(xv.w, sv.w, tv.w);
    ((h4_t*)H)[i4] = h;
}

// ---------------------------------------------------------------------------
// Kernel 4: Wh = fp16(W).
// ---------------------------------------------------------------------------
__global__ __launch_bounds__(256) void k_convert_w(const float* __restrict__ W,
                                                   _Float16* __restrict__ Wh)
{
    const size_t i4 = (size_t)blockIdx.x * 256 + threadIdx.x;
    const float4 wv = ((const float4*)W)[i4];
    h4_t h;
    h.x = (_Float16)wv.x;
    h.y = (_Float16)wv.y;
    h.z = (_Float16)wv.z;
    h.w = (_Float16)wv.w;
    ((h4_t*)Wh)[i4] = h;
}

// ---------------------------------------------------------------------------
// Kernel 5: GEMM  out[m][n] = leaky(sum_k H[m][k]*Wh[n][k] + bias[n])
// m97 structure: 128x128 tile, BK=32, 256 threads (4 waves 2x2), 4x4 MFMA
// tiles/wave of mfma_f32_16x16x32_f16, global_load_lds width-16 staging.
// LDS tiles are unpadded row-major [128][32] halves — required by
// global_load_lds (wave-uniform base + lane*16B).
// ---------------------------------------------------------------------------
__global__ __launch_bounds__(256) void k_gemm(const _Float16* __restrict__ H,
                                              const _Float16* __restrict__ Wh,
                                              const float* __restrict__ bias,
                                              float* __restrict__ out)
{
    __shared__ _Float16 Ah[128 * 32];
    __shared__ _Float16 Bh[128 * 32];

    const int tid  = threadIdx.x;
    const int wave = tid >> 6;
    const int lane = tid & 63;
    const int quad = lane >> 4;   // 0..3
    const int l16  = lane & 15;   // 0..15
    const int wr   = wave >> 1;   // wave row 0..1 (64-row halves)
    const int wc   = wave & 1;    // wave col 0..1

    const int rowBase = blockIdx.y * 128;
    const int colBase = blockIdx.x * 128;

    f32x4 acc[4][4];
#pragma unroll
    for (int i = 0; i < 4; ++i)
#pragma unroll
        for (int j = 0; j < 4; ++j) {
            f32x4 z = {0.f, 0.f, 0.f, 0.f};
            acc[i][j] = z;
        }

    for (int k0 = 0; k0 < IN_DIM; k0 += 32) {
        // ---- stage A,B tiles: 512 x 16B chunks each; 2 chunks/thread/matrix.
        // chunk c -> LDS halves [c*8 .. c*8+8) ; global row = c>>2, k-sub = (c&3)*8.
        // LDS base passed per-wave-uniform; HW adds lane*16B.
#pragma unroll
        for (int it = 0; it < 2; ++it) {
            const int cb    = it * 256 + wave * 64;   // wave-uniform chunk base
            const int chunk = cb + lane;
            const int row   = chunk >> 2;
            const int c8    = (chunk & 3) * 8;
            const _Float16* gA = H  + (size_t)(rowBase + row) * IN_DIM + k0 + c8;
            const _Float16* gB = Wh + (size_t)(colBase + row) * IN_DIM + k0 + c8;
            __builtin_amdgcn_global_load_lds(AS_G(gA), AS_L(Ah + cb * 8), 16, 0, 0);
            __builtin_amdgcn_global_load_lds(AS_G(gB), AS_L(Bh + cb * 8), 16, 0, 0);
        }
        __syncthreads();

        // ---- fragments: A[m=l16][k=quad*8+j] -> contiguous 8 halves (16B)
        h8_t af[4], bf[4];
#pragma unroll
        for (int i = 0; i < 4; ++i)
            af[i] = *(const h8_t*)&Ah[(size_t)(wr * 64 + i * 16 + l16) * 32 + quad * 8];
#pragma unroll
        for (int j = 0; j < 4; ++j)
            bf[j] = *(const h8_t*)&Bh[(size_t)(wc * 64 + j * 16 + l16) * 32 + quad * 8];

#pragma unroll
        for (int i = 0; i < 4; ++i)
#pragma unroll
            for (int j = 0; j < 4; ++j)
                acc[i][j] = __builtin_amdgcn_mfma_f32_16x16x32_f16(af[i], bf[j], acc[i][j], 0, 0, 0);

        __syncthreads();
    }

    // ---- epilogue: bias + LeakyReLU, scalar fp32 stores.
    // C/D layout: col = lane&15, row = quad*4 + reg   (dtype-independent, verified m89)
#pragma unroll
    for (int j = 0; j < 4; ++j) {
        const int col = colBase + wc * 64 + j * 16 + l16;
        const float bj = bias[col];
#pragma unroll
        for (int i = 0; i < 4; ++i) {
            const int row0 = rowBase + wr * 64 + i * 16 + quad * 4;
#pragma unroll
            for (int r = 0; r < 4; ++r) {
                float v = acc[i][j][r] + bj;
                v = (v >= 0.f) ? v : SLOPE * v;
                out[(size_t)(row0 + r) * OUT_DIM + col] = v;
            }
        }
    }
}

// ---------------------------------------------------------------------------
extern "C" void kernel_launch(void* const* d_in, const int* in_sizes, int n_in,
                              void* d_out, int out_size, void* d_ws, size_t ws_size,
                              hipStream_t stream)
{
    const float* x     = (const float*)d_in[0];   // [8192,4096]
    const float* gamma = (const float*)d_in[1];   // [4096]
    const float* beta  = (const float*)d_in[2];   // [4096]
    const float* W     = (const float*)d_in[3];   // [4096,4096] row-major [OUT][IN]
    const float* bias  = (const float*)d_in[4];   // [4096]
    float* out = (float*)d_out;                   // [8192,4096]

    // workspace layout (all 16B-aligned):
    //   H   : B*IN fp16      = 64 MB
    //   Wh  : OUT*IN fp16    = 32 MB
    //   part: 32*2*IN fp32   = 1 MB
    //   scale, shift : IN fp32 each
    char* ws = (char*)d_ws;
    _Float16* Hh = (_Float16*)ws;
    _Float16* Wh = (_Float16*)(ws + (size_t)B_DIM * IN_DIM * sizeof(_Float16));
    float* partial = (float*)(ws + (size_t)B_DIM * IN_DIM * sizeof(_Float16)
                                 + (size_t)OUT_DIM * IN_DIM * sizeof(_Float16));
    float* scale = partial + (size_t)64 * IN_DIM;
    float* shift = scale + IN_DIM;

    k_stats_partial<<<dim3(IN_DIM / 256, B_DIM / 256), 256, 0, stream>>>(x, partial);
    k_stats_final  <<<dim3(IN_DIM / 256), 256, 0, stream>>>(partial, gamma, beta, scale, shift);
    k_convert_h    <<<dim3((unsigned)((size_t)B_DIM * IN_DIM / 4 / 256)), 256, 0, stream>>>(x, scale, shift, Hh);
    k_convert_w    <<<dim3((unsigned)((size_t)OUT_DIM * IN_DIM / 4 / 256)), 256, 0, stream>>>(W, Wh);
    k_gemm         <<<dim3(OUT_DIM / 128, B_DIM / 128), 256, 0, stream>>>(Hh, Wh, bias, out);
}

// Round 2
// 627.503 us; speedup vs baseline: 1.0117x; 1.0117x over previous
//
#include <hip/hip_runtime.h>
#include <cstdint>
#include <cstddef>

// ---- types ----
typedef _Float16 h8_t  __attribute__((ext_vector_type(8)));
typedef _Float16 h4_t  __attribute__((ext_vector_type(4)));
typedef float    f32x4 __attribute__((ext_vector_type(4)));

#define B_DIM   8192
#define IN_DIM  4096
#define OUT_DIM 4096
#define BN_EPS  1e-5f
#define SLOPE   0.01f

// address-space casts for global_load_lds
#define AS_G(p) ((__attribute__((address_space(1))) void*)(p))
#define AS_L(p) ((__attribute__((address_space(3))) void*)(p))

// ---------------------------------------------------------------------------
// Kernel 1: column partial sums via float4. grid (IN/1024, 128), block 256.
// Thread owns one float4 column-group, loops 64 rows (4 KB contiguous per
// block per row-step -> fully coalesced dwordx4).
// ---------------------------------------------------------------------------
__global__ __launch_bounds__(256) void k_stats_partial(const float* __restrict__ x,
                                                       float* __restrict__ partial)
{
    const int col4 = blockIdx.x * 256 + threadIdx.x;      // float4 index in row (0..1023)
    const int r0   = blockIdx.y * 64;
    const f32x4* xr = (const f32x4*)x + (size_t)r0 * (IN_DIM / 4) + col4;
    f32x4 s  = {0.f, 0.f, 0.f, 0.f};
    f32x4 sq = {0.f, 0.f, 0.f, 0.f};
#pragma unroll 8
    for (int r = 0; r < 64; ++r) {
        f32x4 v = xr[(size_t)r * (IN_DIM / 4)];
        s  += v;
        sq += v * v;
    }
    f32x4* ps = (f32x4*)partial;
    ps[(size_t)(blockIdx.y * 2 + 0) * (IN_DIM / 4) + col4] = s;
    ps[(size_t)(blockIdx.y * 2 + 1) * (IN_DIM / 4) + col4] = sq;
}

// ---------------------------------------------------------------------------
// Kernel 2: reduce 128 partials -> scale s[i] = gamma*rsqrt(var+eps),
// shift t[i] = beta - mean*s.
// ---------------------------------------------------------------------------
__global__ __launch_bounds__(256) void k_stats_final(const float* __restrict__ partial,
                                                     const float* __restrict__ gamma,
                                                     const float* __restrict__ beta,
                                                     float* __restrict__ scale,
                                                     float* __restrict__ shiftv)
{
    const int col = blockIdx.x * 256 + threadIdx.x;
    float s = 0.f, sq = 0.f;
#pragma unroll 8
    for (int c = 0; c < 128; ++c) {
        s  += partial[(size_t)(c * 2 + 0) * IN_DIM + col];
        sq += partial[(size_t)(c * 2 + 1) * IN_DIM + col];
    }
    const float inv  = 1.0f / (float)B_DIM;
    const float mean = s * inv;
    const float var  = sq * inv - mean * mean;   // biased
    const float sc   = gamma[col] * rsqrtf(var + BN_EPS);
    scale[col]  = sc;
    shiftv[col] = beta[col] - mean * sc;
}

// ---------------------------------------------------------------------------
// Kernel 3: Xh = fp16(x). 8 floats/thread: 2x float4 in, one 16B h8 out.
// No dependency on stats (BN folded into W).
// ---------------------------------------------------------------------------
__global__ __launch_bounds__(256) void k_cast_x(const float* __restrict__ x,
                                                _Float16* __restrict__ Xh)
{
    const size_t i8 = (size_t)blockIdx.x * 256 + threadIdx.x;
    const f32x4 a = ((const f32x4*)x)[i8 * 2 + 0];
    const f32x4 b = ((const f32x4*)x)[i8 * 2 + 1];
    h8_t h;
    h[0] = (_Float16)a[0]; h[1] = (_Float16)a[1];
    h[2] = (_Float16)a[2]; h[3] = (_Float16)a[3];
    h[4] = (_Float16)b[0]; h[5] = (_Float16)b[1];
    h[6] = (_Float16)b[2]; h[7] = (_Float16)b[3];
    ((h8_t*)Xh)[i8] = h;
}

// ---------------------------------------------------------------------------
// Kernel 4: per W-row o:  Wh[o,i] = fp16(W[o,i]*s[i]);  bp[o] = b[o] + sum_i t[i]*W[o,i]
// One wave per row, float4 loads, shuffle-reduce for the dot.
// ---------------------------------------------------------------------------
__global__ __launch_bounds__(256) void k_prep_w(const float* __restrict__ W,
                                                const float* __restrict__ scale,
                                                const float* __restrict__ shiftv,
                                                const float* __restrict__ b,
                                                _Float16* __restrict__ Wh,
                                                float* __restrict__ bp)
{
    const int wave = threadIdx.x >> 6;
    const int lane = threadIdx.x & 63;
    const int row  = blockIdx.x * 4 + wave;
    const f32x4* wr = (const f32x4*)(W + (size_t)row * IN_DIM);
    const f32x4* sv = (const f32x4*)scale;
    const f32x4* tv = (const f32x4*)shiftv;
    h4_t* out = (h4_t*)(Wh + (size_t)row * IN_DIM);
    float dot = 0.f;
#pragma unroll
    for (int it = 0; it < IN_DIM / 4 / 64; ++it) {   // 16 iters
        const int c = it * 64 + lane;
        const f32x4 w = wr[c];
        const f32x4 s = sv[c];
        const f32x4 t = tv[c];
        dot += w[0] * t[0] + w[1] * t[1] + w[2] * t[2] + w[3] * t[3];
        h4_t h;
        h[0] = (_Float16)(w[0] * s[0]);
        h[1] = (_Float16)(w[1] * s[1]);
        h[2] = (_Float16)(w[2] * s[2]);
        h[3] = (_Float16)(w[3] * s[3]);
        out[c] = h;
    }
#pragma unroll
    for (int off = 32; off >= 1; off >>= 1)
        dot += __shfl_down(dot, off, 64);
    if (lane == 0) bp[row] = b[row] + dot;
}

// ---------------------------------------------------------------------------
// Kernel 5: GEMM  out[m][n] = leaky(sum_k Xh[m][k]*Wh[n][k] + bp[n])
// m97 structure + LDS XOR swizzle. 128x128 tile, BK=32, 4 waves 2x2,
// 4x4 mfma_f32_16x16x32_f16 per wave, global_load_lds width-16 staging.
//
// Swizzle: chunk c (row=c>>2, kq=c&3) fetches global k-segment
// ksel = kq ^ ((row>>1)&3); fragment read applies the inverse XOR.
// Bank group per lane = 16*(r&1) + 4*(quad^((r>>1)&3)) -> 8 groups x 2 lanes
// = 2-way (free, m136) instead of the previous 8-way.
// ---------------------------------------------------------------------------
__global__ __launch_bounds__(256) void k_gemm(const _Float16* __restrict__ H,
                                              const _Float16* __restrict__ Wh,
                                              const float* __restrict__ bias,
                                              float* __restrict__ out)
{
    __shared__ _Float16 Ah[128 * 32];
    __shared__ _Float16 Bh[128 * 32];

    const int tid  = threadIdx.x;
    const int wave = tid >> 6;
    const int lane = tid & 63;
    const int quad = lane >> 4;   // 0..3
    const int l16  = lane & 15;   // 0..15
    const int wr   = wave >> 1;   // wave row 0..1
    const int wc   = wave & 1;    // wave col 0..1
    const int xr   = (l16 >> 1) & 3;          // swizzle term for fragment reads

    const int rowBase = blockIdx.y * 128;
    const int colBase = blockIdx.x * 128;

    f32x4 acc[4][4];
#pragma unroll
    for (int i = 0; i < 4; ++i)
#pragma unroll
        for (int j = 0; j < 4; ++j) {
            f32x4 z = {0.f, 0.f, 0.f, 0.f};
            acc[i][j] = z;
        }

    for (int k0 = 0; k0 < IN_DIM; k0 += 32) {
#pragma unroll
        for (int it = 0; it < 2; ++it) {
            const int cb    = it * 256 + wave * 64;   // wave-uniform chunk base
            const int chunk = cb + lane;
            const int row   = chunk >> 2;
            const int kq    = chunk & 3;
            const int ksel  = kq ^ ((row >> 1) & 3);  // swizzled global k-segment
            const _Float16* gA = H  + (size_t)(rowBase + row) * IN_DIM + k0 + ksel * 8;
            const _Float16* gB = Wh + (size_t)(colBase + row) * IN_DIM + k0 + ksel * 8;
            __builtin_amdgcn_global_load_lds(AS_G(gA), AS_L(Ah + cb * 8), 16, 0, 0);
            __builtin_amdgcn_global_load_lds(AS_G(gB), AS_L(Bh + cb * 8), 16, 0, 0);
        }
        __syncthreads();

        // fragment for k-segment `quad` of row r lives at kq = quad ^ ((r>>1)&3)
        h8_t af[4], bf[4];
#pragma unroll
        for (int i = 0; i < 4; ++i) {
            const int row = wr * 64 + i * 16 + l16;
            af[i] = *(const h8_t*)&Ah[(size_t)row * 32 + (quad ^ xr) * 8];
        }
#pragma unroll
        for (int j = 0; j < 4; ++j) {
            const int row = wc * 64 + j * 16 + l16;
            bf[j] = *(const h8_t*)&Bh[(size_t)row * 32 + (quad ^ xr) * 8];
        }

#pragma unroll
        for (int i = 0; i < 4; ++i)
#pragma unroll
            for (int j = 0; j < 4; ++j)
                acc[i][j] = __builtin_amdgcn_mfma_f32_16x16x32_f16(af[i], bf[j], acc[i][j], 0, 0, 0);

        __syncthreads();
    }

    // epilogue: bias + LeakyReLU. C/D: col = lane&15, row = quad*4 + reg.
#pragma unroll
    for (int j = 0; j < 4; ++j) {
        const int col = colBase + wc * 64 + j * 16 + l16;
        const float bj = bias[col];
#pragma unroll
        for (int i = 0; i < 4; ++i) {
            const int row0 = rowBase + wr * 64 + i * 16 + quad * 4;
#pragma unroll
            for (int r = 0; r < 4; ++r) {
                float v = acc[i][j][r] + bj;
                v = (v >= 0.f) ? v : SLOPE * v;
                out[(size_t)(row0 + r) * OUT_DIM + col] = v;
            }
        }
    }
}

// ---------------------------------------------------------------------------
extern "C" void kernel_launch(void* const* d_in, const int* in_sizes, int n_in,
                              void* d_out, int out_size, void* d_ws, size_t ws_size,
                              hipStream_t stream)
{
    const float* x     = (const float*)d_in[0];   // [8192,4096]
    const float* gamma = (const float*)d_in[1];   // [4096]
    const float* beta  = (const float*)d_in[2];   // [4096]
    const float* W     = (const float*)d_in[3];   // [4096,4096] row-major [OUT][IN]
    const float* bias  = (const float*)d_in[4];   // [4096]
    float* out = (float*)d_out;                   // [8192,4096]

    // workspace layout (16B-aligned):
    //   Xh  : B*IN fp16        = 64 MB
    //   Wh  : OUT*IN fp16      = 32 MB
    //   part: 128*2*IN fp32    = 4 MB
    //   scale, shiftv : IN fp32 ; bp : OUT fp32
    char* ws = (char*)d_ws;
    _Float16* Xh = (_Float16*)ws;
    _Float16* Wh = (_Float16*)(ws + (size_t)B_DIM * IN_DIM * sizeof(_Float16));
    float* partial = (float*)(ws + (size_t)B_DIM * IN_DIM * sizeof(_Float16)
                                 + (size_t)OUT_DIM * IN_DIM * sizeof(_Float16));
    float* scale  = partial + (size_t)256 * IN_DIM;
    float* shiftv = scale + IN_DIM;
    float* bp     = shiftv + IN_DIM;

    k_cast_x       <<<dim3((unsigned)((size_t)B_DIM * IN_DIM / 8 / 256)), 256, 0, stream>>>(x, Xh);
    k_stats_partial<<<dim3(IN_DIM / 1024, B_DIM / 64), 256, 0, stream>>>(x, partial);
    k_stats_final  <<<dim3(IN_DIM / 256), 256, 0, stream>>>(partial, gamma, beta, scale, shiftv);
    k_prep_w       <<<dim3(OUT_DIM / 4), 256, 0, stream>>>(W, scale, shiftv, bias, Wh, bp);
    k_gemm         <<<dim3(OUT_DIM / 128, B_DIM / 128), 256, 0, stream>>>(Xh, Wh, bp, out);
}

// Round 3
// 607.586 us; speedup vs baseline: 1.0449x; 1.0328x over previous
//
#include <hip/hip_runtime.h>
#include <cstdint>
#include <cstddef>

// ---- types ----
typedef _Float16 h8_t  __attribute__((ext_vector_type(8)));
typedef _Float16 h4_t  __attribute__((ext_vector_type(4)));
typedef float    f32x4 __attribute__((ext_vector_type(4)));

#define B_DIM   8192
#define IN_DIM  4096
#define OUT_DIM 4096
#define BN_EPS  1e-5f
#define SLOPE   0.01f

// address-space casts for global_load_lds
#define AS_G(p) ((__attribute__((address_space(1))) void*)(p))
#define AS_L(p) ((__attribute__((address_space(3))) void*)(p))

// ---------------------------------------------------------------------------
// Kernel 1 (fused): Xh = fp16(x)  AND  per-column partial sum/sumsq.
// Reads x exactly once (vs twice before). Block covers 32 rows x 2048 cols;
// thread t owns 8 consecutive cols (two float4 loads -> one 16B h8 store),
// accumulating s/sq in registers across the 32 rows.
// grid (IN/2048, B/32) = (2, 256). partial has 256 chunk-pairs.
// ---------------------------------------------------------------------------
__global__ __launch_bounds__(256) void k_fused_x(const float* __restrict__ x,
                                                 _Float16* __restrict__ Xh,
                                                 float* __restrict__ partial)
{
    const int col8 = blockIdx.x * 256 + threadIdx.x;   // float8 index in row
    const int r0   = blockIdx.y * 32;
    const f32x4* xr = (const f32x4*)x + (size_t)r0 * (IN_DIM / 4) + col8 * 2;
    h8_t* xo = (h8_t*)Xh + (size_t)r0 * (IN_DIM / 8) + col8;

    f32x4 sa  = {0.f, 0.f, 0.f, 0.f}, sb  = {0.f, 0.f, 0.f, 0.f};
    f32x4 qa  = {0.f, 0.f, 0.f, 0.f}, qb  = {0.f, 0.f, 0.f, 0.f};
#pragma unroll 4
    for (int r = 0; r < 32; ++r) {
        const f32x4 a = xr[(size_t)r * (IN_DIM / 4) + 0];
        const f32x4 b = xr[(size_t)r * (IN_DIM / 4) + 1];
        sa += a;  qa += a * a;
        sb += b;  qb += b * b;
        h8_t h;
        h[0] = (_Float16)a[0]; h[1] = (_Float16)a[1];
        h[2] = (_Float16)a[2]; h[3] = (_Float16)a[3];
        h[4] = (_Float16)b[0]; h[5] = (_Float16)b[1];
        h[6] = (_Float16)b[2]; h[7] = (_Float16)b[3];
        xo[(size_t)r * (IN_DIM / 8)] = h;
    }
    f32x4* ps = (f32x4*)partial;
    const size_t rowS = (size_t)(blockIdx.y * 2 + 0) * (IN_DIM / 4);
    const size_t rowQ = (size_t)(blockIdx.y * 2 + 1) * (IN_DIM / 4);
    ps[rowS + col8 * 2 + 0] = sa;
    ps[rowS + col8 * 2 + 1] = sb;
    ps[rowQ + col8 * 2 + 0] = qa;
    ps[rowQ + col8 * 2 + 1] = qb;
}

// ---------------------------------------------------------------------------
// Kernel 2: reduce 256 partial chunk-pairs -> scale/shift per column.
// 64 blocks; block owns 64 cols; 4 wave-groups each sum 64 chunks, then
// LDS-reduce across groups.
// ---------------------------------------------------------------------------
__global__ __launch_bounds__(256) void k_stats_final(const float* __restrict__ partial,
                                                     const float* __restrict__ gamma,
                                                     const float* __restrict__ beta,
                                                     float* __restrict__ scale,
                                                     float* __restrict__ shiftv)
{
    __shared__ float rs[4][64];
    __shared__ float rq[4][64];
    const int g   = threadIdx.x >> 6;          // chunk group 0..3
    const int l   = threadIdx.x & 63;
    const int col = blockIdx.x * 64 + l;
    float s = 0.f, sq = 0.f;
#pragma unroll 8
    for (int c = 0; c < 64; ++c) {
        const int ch = g * 64 + c;
        s  += partial[(size_t)(ch * 2 + 0) * IN_DIM + col];
        sq += partial[(size_t)(ch * 2 + 1) * IN_DIM + col];
    }
    rs[g][l] = s;
    rq[g][l] = sq;
    __syncthreads();
    if (g == 0) {
        s  = rs[0][l] + rs[1][l] + rs[2][l] + rs[3][l];
        sq = rq[0][l] + rq[1][l] + rq[2][l] + rq[3][l];
        const float inv  = 1.0f / (float)B_DIM;
        const float mean = s * inv;
        const float var  = sq * inv - mean * mean;   // biased
        const float sc   = gamma[col] * rsqrtf(var + BN_EPS);
        scale[col]  = sc;
        shiftv[col] = beta[col] - mean * sc;
    }
}

// ---------------------------------------------------------------------------
// Kernel 3: per W-row o:  Wh[o,i] = fp16(W[o,i]*s[i]);  bp[o] = b[o] + sum_i t[i]*W[o,i]
// One wave per row, float4 loads, shuffle-reduce for the dot.
// ---------------------------------------------------------------------------
__global__ __launch_bounds__(256) void k_prep_w(const float* __restrict__ W,
                                                const float* __restrict__ scale,
                                                const float* __restrict__ shiftv,
                                                const float* __restrict__ b,
                                                _Float16* __restrict__ Wh,
                                                float* __restrict__ bp)
{
    const int wave = threadIdx.x >> 6;
    const int lane = threadIdx.x & 63;
    const int row  = blockIdx.x * 4 + wave;
    const f32x4* wr = (const f32x4*)(W + (size_t)row * IN_DIM);
    const f32x4* sv = (const f32x4*)scale;
    const f32x4* tv = (const f32x4*)shiftv;
    h4_t* out = (h4_t*)(Wh + (size_t)row * IN_DIM);
    float dot = 0.f;
#pragma unroll
    for (int it = 0; it < IN_DIM / 4 / 64; ++it) {   // 16 iters
        const int c = it * 64 + lane;
        const f32x4 w = wr[c];
        const f32x4 s = sv[c];
        const f32x4 t = tv[c];
        dot += w[0] * t[0] + w[1] * t[1] + w[2] * t[2] + w[3] * t[3];
        h4_t h;
        h[0] = (_Float16)(w[0] * s[0]);
        h[1] = (_Float16)(w[1] * s[1]);
        h[2] = (_Float16)(w[2] * s[2]);
        h[3] = (_Float16)(w[3] * s[3]);
        out[c] = h;
    }
#pragma unroll
    for (int off = 32; off >= 1; off >>= 1)
        dot += __shfl_down(dot, off, 64);
    if (lane == 0) bp[row] = b[row] + dot;
}

// ---------------------------------------------------------------------------
// Kernel 4: GEMM  out[m][n] = leaky(sum_k Xh[m][k]*Wh[n][k] + bp[n])
// m97 structure + LDS XOR swizzle (conflicts measured 0). 128x128 tile,
// BK=32, 4 waves 2x2, 4x4 mfma_f32_16x16x32_f16, global_load_lds width-16.
// ---------------------------------------------------------------------------
__global__ __launch_bounds__(256) void k_gemm(const _Float16* __restrict__ H,
                                              const _Float16* __restrict__ Wh,
                                              const float* __restrict__ bias,
                                              float* __restrict__ out)
{
    __shared__ _Float16 Ah[128 * 32];
    __shared__ _Float16 Bh[128 * 32];

    const int tid  = threadIdx.x;
    const int wave = tid >> 6;
    const int lane = tid & 63;
    const int quad = lane >> 4;   // 0..3
    const int l16  = lane & 15;   // 0..15
    const int wr   = wave >> 1;   // wave row 0..1
    const int wc   = wave & 1;    // wave col 0..1
    const int xr   = (l16 >> 1) & 3;          // swizzle term for fragment reads

    const int rowBase = blockIdx.y * 128;
    const int colBase = blockIdx.x * 128;

    f32x4 acc[4][4];
#pragma unroll
    for (int i = 0; i < 4; ++i)
#pragma unroll
        for (int j = 0; j < 4; ++j) {
            f32x4 z = {0.f, 0.f, 0.f, 0.f};
            acc[i][j] = z;
        }

    for (int k0 = 0; k0 < IN_DIM; k0 += 32) {
#pragma unroll
        for (int it = 0; it < 2; ++it) {
            const int cb    = it * 256 + wave * 64;   // wave-uniform chunk base
            const int chunk = cb + lane;
            const int row   = chunk >> 2;
            const int kq    = chunk & 3;
            const int ksel  = kq ^ ((row >> 1) & 3);  // swizzled global k-segment
            const _Float16* gA = H  + (size_t)(rowBase + row) * IN_DIM + k0 + ksel * 8;
            const _Float16* gB = Wh + (size_t)(colBase + row) * IN_DIM + k0 + ksel * 8;
            __builtin_amdgcn_global_load_lds(AS_G(gA), AS_L(Ah + cb * 8), 16, 0, 0);
            __builtin_amdgcn_global_load_lds(AS_G(gB), AS_L(Bh + cb * 8), 16, 0, 0);
        }
        __syncthreads();

        h8_t af[4], bf[4];
#pragma unroll
        for (int i = 0; i < 4; ++i) {
            const int row = wr * 64 + i * 16 + l16;
            af[i] = *(const h8_t*)&Ah[(size_t)row * 32 + (quad ^ xr) * 8];
        }
#pragma unroll
        for (int j = 0; j < 4; ++j) {
            const int row = wc * 64 + j * 16 + l16;
            bf[j] = *(const h8_t*)&Bh[(size_t)row * 32 + (quad ^ xr) * 8];
        }

#pragma unroll
        for (int i = 0; i < 4; ++i)
#pragma unroll
            for (int j = 0; j < 4; ++j)
                acc[i][j] = __builtin_amdgcn_mfma_f32_16x16x32_f16(af[i], bf[j], acc[i][j], 0, 0, 0);

        __syncthreads();
    }

    // epilogue: bias + LeakyReLU. C/D: col = lane&15, row = quad*4 + reg.
#pragma unroll
    for (int j = 0; j < 4; ++j) {
        const int col = colBase + wc * 64 + j * 16 + l16;
        const float bj = bias[col];
#pragma unroll
        for (int i = 0; i < 4; ++i) {
            const int row0 = rowBase + wr * 64 + i * 16 + quad * 4;
#pragma unroll
            for (int r = 0; r < 4; ++r) {
                float v = acc[i][j][r] + bj;
                v = (v >= 0.f) ? v : SLOPE * v;
                out[(size_t)(row0 + r) * OUT_DIM + col] = v;
            }
        }
    }
}

// ---------------------------------------------------------------------------
extern "C" void kernel_launch(void* const* d_in, const int* in_sizes, int n_in,
                              void* d_out, int out_size, void* d_ws, size_t ws_size,
                              hipStream_t stream)
{
    const float* x     = (const float*)d_in[0];   // [8192,4096]
    const float* gamma = (const float*)d_in[1];   // [4096]
    const float* beta  = (const float*)d_in[2];   // [4096]
    const float* W     = (const float*)d_in[3];   // [4096,4096] row-major [OUT][IN]
    const float* bias  = (const float*)d_in[4];   // [4096]
    float* out = (float*)d_out;                   // [8192,4096]

    // workspace layout (16B-aligned):
    //   Xh  : B*IN fp16        = 64 MB
    //   Wh  : OUT*IN fp16      = 32 MB
    //   part: 512*IN fp32      = 8 MB   (256 chunk-pairs)
    //   scale, shiftv : IN fp32 ; bp : OUT fp32
    char* ws = (char*)d_ws;
    _Float16* Xh = (_Float16*)ws;
    _Float16* Wh = (_Float16*)(ws + (size_t)B_DIM * IN_DIM * sizeof(_Float16));
    float* partial = (float*)(ws + (size_t)B_DIM * IN_DIM * sizeof(_Float16)
                                 + (size_t)OUT_DIM * IN_DIM * sizeof(_Float16));
    float* scale  = partial + (size_t)512 * IN_DIM;
    float* shiftv = scale + IN_DIM;
    float* bp     = shiftv + IN_DIM;

    k_fused_x    <<<dim3(IN_DIM / 2048, B_DIM / 32), 256, 0, stream>>>(x, Xh, partial);
    k_stats_final<<<dim3(IN_DIM / 64), 256, 0, stream>>>(partial, gamma, beta, scale, shiftv);
    k_prep_w     <<<dim3(OUT_DIM / 4), 256, 0, stream>>>(W, scale, shiftv, bias, Wh, bp);
    k_gemm       <<<dim3(OUT_DIM / 128, B_DIM / 128), 256, 0, stream>>>(Xh, Wh, bp, out);
}